// Round 1
// baseline (904.119 us; speedup 1.0000x reference)
//
#include <hip/hip_runtime.h>

#define N_NODES 100000
#define N_EDGES 1600000

// ---------------------------------------------------------------------------
// deg histogram: deg[dst[e]] += 1  (deg buffer pre-zeroed via memsetAsync)
__global__ void deg_kernel(const int* __restrict__ dst, float* __restrict__ deg, int E) {
    int e = blockIdx.x * blockDim.x + threadIdx.x;
    if (e < E) atomicAdd(&deg[dst[e]], 1.0f);
}

// deg -> dinv in place: dinv = rsqrt(deg + 1)   (+1 = self loop)
__global__ void dinv_kernel(float* __restrict__ deg, int n) {
    int i = blockIdx.x * blockDim.x + threadIdx.x;
    if (i < n) deg[i] = rsqrtf(deg[i] + 1.0f);
}

// ---------------------------------------------------------------------------
// out[n, FOUT] = in[n, FIN] @ W[FIN, FOUT]    (no bias here; bias in finalize)
template <int FIN, int FOUT>
__global__ void gemm_kernel(const float* __restrict__ in, const float* __restrict__ W,
                            float* __restrict__ out, int n) {
    __shared__ float sW[FIN * FOUT];
    for (int i = threadIdx.x; i < FIN * FOUT; i += blockDim.x) sW[i] = W[i];
    __syncthreads();
    constexpr int ROWS = 256 / FOUT;
    int r = blockIdx.x * ROWS + threadIdx.x / FOUT;
    int c = threadIdx.x % FOUT;
    if (r >= n) return;
    float acc = 0.f;
#pragma unroll
    for (int k = 0; k < FIN; k++) acc += in[r * FIN + k] * sW[k * FOUT + c];
    out[r * FOUT + c] = acc;
}

// ---------------------------------------------------------------------------
// For each real edge e, feature f:  agg[dst*F+f] += dinv[src]*dinv[dst]*h[src*F+f]
template <int F>
__global__ void edge_kernel(const int* __restrict__ src, const int* __restrict__ dst,
                            const float* __restrict__ dinv, const float* __restrict__ h,
                            float* __restrict__ agg, int E) {
    int tid = blockIdx.x * blockDim.x + threadIdx.x;
    int e = tid / F;
    int f = tid % F;
    if (e >= E) return;
    int s = src[e];
    int d = dst[e];
    float w = dinv[s] * dinv[d];
    atomicAdd(&agg[d * F + f], w * h[s * F + f]);
}

// ---------------------------------------------------------------------------
// agg[i,f] = (relu?)(agg[i,f] + dinv[i]^2 * h[i,f] + b[f])   (self loop + bias)
template <int F, bool RELU>
__global__ void finalize_kernel(const float* __restrict__ h, const float* __restrict__ dinv,
                                const float* __restrict__ b, float* __restrict__ agg, int n) {
    int tid = blockIdx.x * blockDim.x + threadIdx.x;
    if (tid >= n * F) return;
    int i = tid / F;
    int f = tid % F;
    float di = dinv[i];
    float v = agg[tid] + di * di * h[tid] + b[f];
    if (RELU) v = fmaxf(v, 0.f);
    agg[tid] = v;
}

// ---------------------------------------------------------------------------
extern "C" void kernel_launch(void* const* d_in, const int* in_sizes, int n_in,
                              void* d_out, int out_size, void* d_ws, size_t ws_size,
                              hipStream_t stream) {
    const float* x  = (const float*)d_in[0];           // [N, 64]
    const int* ei   = (const int*)d_in[1];             // [2, E]
    const float* W1 = (const float*)d_in[2];           // [64, 64]
    const float* b1 = (const float*)d_in[3];
    const float* W2 = (const float*)d_in[4];           // [64, 32]
    const float* b2 = (const float*)d_in[5];
    const float* W3 = (const float*)d_in[6];           // [32, 2]
    const float* b3 = (const float*)d_in[7];
    float* out = (float*)d_out;                        // [N, 2]

    const int N = N_NODES;
    const int E = N_EDGES;
    const int* src = ei;         // edge_index[0]
    const int* dst = ei + E;     // edge_index[1]

    // workspace layout (floats): dinv[N] | A[N*64] | B[N*64]
    float* dinv = (float*)d_ws;
    float* A = dinv + N;
    float* B = A + N * 64;

    const int T = 256;

    // --- degree / dinv ---
    hipMemsetAsync(dinv, 0, N * sizeof(float), stream);
    deg_kernel<<<(E + T - 1) / T, T, 0, stream>>>(dst, dinv, E);
    dinv_kernel<<<(N + T - 1) / T, T, 0, stream>>>(dinv, N);

    // --- layer 1: x[N,64] @ W1 -> A; aggregate -> B; relu(B + dinv^2*A + b1) ---
    gemm_kernel<64, 64><<<(N + 3) / 4, T, 0, stream>>>(x, W1, A, N);
    hipMemsetAsync(B, 0, (size_t)N * 64 * sizeof(float), stream);
    {
        long long tot = (long long)E * 64;
        edge_kernel<64><<<(int)((tot + T - 1) / T), T, 0, stream>>>(src, dst, dinv, A, B, E);
    }
    finalize_kernel<64, true><<<(N * 64 + T - 1) / T, T, 0, stream>>>(A, dinv, b1, B, N);

    // --- layer 2: B[N,64] @ W2 -> A[N,32]; aggregate -> B; relu ---
    gemm_kernel<64, 32><<<(N + 7) / 8, T, 0, stream>>>(B, W2, A, N);
    hipMemsetAsync(B, 0, (size_t)N * 32 * sizeof(float), stream);
    {
        long long tot = (long long)E * 32;
        edge_kernel<32><<<(int)((tot + T - 1) / T), T, 0, stream>>>(src, dst, dinv, A, B, E);
    }
    finalize_kernel<32, true><<<(N * 32 + T - 1) / T, T, 0, stream>>>(A, dinv, b2, B, N);

    // --- layer 3: B[N,32] @ W3 -> A[N,2]; aggregate -> d_out; + bias (no relu) ---
    gemm_kernel<32, 2><<<(N + 127) / 128, T, 0, stream>>>(B, W3, A, N);
    hipMemsetAsync(out, 0, (size_t)N * 2 * sizeof(float), stream);
    {
        long long tot = (long long)E * 2;
        edge_kernel<2><<<(int)((tot + T - 1) / T), T, 0, stream>>>(src, dst, dinv, A, out, E);
    }
    finalize_kernel<2, false><<<(N * 2 + T - 1) / T, T, 0, stream>>>(A, dinv, b3, out, N);
}

// Round 2
// 599.066 us; speedup vs baseline: 1.5092x; 1.5092x over previous
//
#include <hip/hip_runtime.h>

#define N_NODES 100000
#define N_EDGES 1600000

// ---------------------------------------------------------------------------
// int in-degree histogram (counts pre-zeroed)
__global__ void hist_kernel(const int* __restrict__ dst, int* __restrict__ counts, int E) {
    int e = blockIdx.x * blockDim.x + threadIdx.x;
    if (e < E) atomicAdd(&counts[dst[e]], 1);
}

// dinv[i] = rsqrt(indeg + 1)   (+1 = self loop)
__global__ void dinv_kernel(const int* __restrict__ counts, float* __restrict__ dinv, int n) {
    int i = blockIdx.x * blockDim.x + threadIdx.x;
    if (i < n) dinv[i] = rsqrtf((float)counts[i] + 1.0f);
}

// --- 3-kernel exclusive scan of counts[n] -> rowptr[n] ----------------------
__global__ void scan1_kernel(const int* __restrict__ counts, int* __restrict__ rowptr,
                             int* __restrict__ bsums, int n) {
    __shared__ int s[256];
    int i = blockIdx.x * 256 + threadIdx.x;
    int v = (i < n) ? counts[i] : 0;
    s[threadIdx.x] = v;
    __syncthreads();
    for (int off = 1; off < 256; off <<= 1) {
        int t = (threadIdx.x >= off) ? s[threadIdx.x - off] : 0;
        __syncthreads();
        s[threadIdx.x] += t;
        __syncthreads();
    }
    if (i < n) rowptr[i] = s[threadIdx.x] - v;           // exclusive
    if (threadIdx.x == 255) bsums[blockIdx.x] = s[255];  // block total
}

__global__ void scan2_kernel(int* __restrict__ bsums, int nb) {
    __shared__ int s[512];
    int t = threadIdx.x;
    int v = (t < nb) ? bsums[t] : 0;
    s[t] = v;
    __syncthreads();
    for (int off = 1; off < 512; off <<= 1) {
        int u = (t >= off) ? s[t - off] : 0;
        __syncthreads();
        s[t] += u;
        __syncthreads();
    }
    if (t < nb) bsums[t] = s[t] - v;                     // exclusive
}

__global__ void scan3_kernel(int* __restrict__ rowptr, const int* __restrict__ bsums, int n) {
    int i = blockIdx.x * 256 + threadIdx.x;
    if (i < n) rowptr[i] += bsums[blockIdx.x];
}

// --- scatter edges into CSR order; rowptr is consumed as cursors ------------
// After this kernel rowptr[d] == original rowptr[d+1]  (i.e. row END of d).
__global__ void scatter_kernel(const int* __restrict__ src, const int* __restrict__ dst,
                               const float* __restrict__ dinv, int* __restrict__ rowptr,
                               int2* __restrict__ edges, int E) {
    int e = blockIdx.x * blockDim.x + threadIdx.x;
    if (e >= E) return;
    int s = src[e];
    int d = dst[e];
    float w = dinv[s] * dinv[d];
    int pos = atomicAdd(&rowptr[d], 1);
    edges[pos] = make_int2(s, __float_as_int(w));
}

// ---------------------------------------------------------------------------
// out[n, FOUT] = in[n, FIN] @ W[FIN, FOUT]
template <int FIN, int FOUT>
__global__ void gemm_kernel(const float* __restrict__ in, const float* __restrict__ W,
                            float* __restrict__ out, int n) {
    __shared__ float sW[FIN * FOUT];
    for (int i = threadIdx.x; i < FIN * FOUT; i += blockDim.x) sW[i] = W[i];
    __syncthreads();
    constexpr int ROWS = 256 / FOUT;
    int r = blockIdx.x * ROWS + threadIdx.x / FOUT;
    int c = threadIdx.x % FOUT;
    if (r >= n) return;
    float acc = 0.f;
#pragma unroll
    for (int k = 0; k < FIN; k++) acc += in[r * FIN + k] * sW[k * FOUT + c];
    out[r * FOUT + c] = acc;
}

// ---------------------------------------------------------------------------
// Gather-side aggregation, zero atomics, finalize fused.
// Each group of F consecutive lanes owns one dst node; lane = feature.
// rowend[d] = end of d's edge range; start = rowend[d-1] (0 for d==0).
template <int F, bool RELU>
__global__ void agg_kernel(const int2* __restrict__ edges, const int* __restrict__ rowend,
                           const float* __restrict__ dinv, const float* __restrict__ h,
                           const float* __restrict__ b, float* __restrict__ out, int n) {
    int g = (blockIdx.x * blockDim.x + threadIdx.x) / F;   // node
    int lane = threadIdx.x % F;                            // feature
    if (g >= n) return;
    int end = rowend[g];
    int start = (g == 0) ? 0 : rowend[g - 1];
    float acc = 0.f;
    for (int j = start; j < end; j++) {
        int2 e = edges[j];
        acc += __int_as_float(e.y) * h[e.x * F + lane];
    }
    float di = dinv[g];
    float v = acc + di * di * h[g * F + lane] + b[lane];
    out[g * F + lane] = RELU ? fmaxf(v, 0.f) : v;
}

// ---------------------------------------------------------------------------
extern "C" void kernel_launch(void* const* d_in, const int* in_sizes, int n_in,
                              void* d_out, int out_size, void* d_ws, size_t ws_size,
                              hipStream_t stream) {
    const float* x  = (const float*)d_in[0];           // [N, 64]
    const int* ei   = (const int*)d_in[1];             // [2, E]
    const float* W1 = (const float*)d_in[2];
    const float* b1 = (const float*)d_in[3];
    const float* W2 = (const float*)d_in[4];
    const float* b2 = (const float*)d_in[5];
    const float* W3 = (const float*)d_in[6];
    const float* b3 = (const float*)d_in[7];
    float* out = (float*)d_out;                        // [N, 2]

    const int N = N_NODES;
    const int E = N_EDGES;
    const int* src = ei;
    const int* dst = ei + E;

    // workspace layout (16B-aligned carve)
    char* p = (char*)d_ws;
    int*   counts = (int*)p;              p += ((size_t)N * 4 + 15) / 16 * 16;
    int*   rowptr = (int*)p;              p += ((size_t)N * 4 + 15) / 16 * 16;
    int*   bsums  = (int*)p;              p += 512 * 4;
    float* dinv   = (float*)p;            p += ((size_t)N * 4 + 15) / 16 * 16;
    int2*  edges  = (int2*)p;             p += (size_t)E * 8;
    float* A      = (float*)p;            p += (size_t)N * 64 * 4;
    float* B      = (float*)p;

    const int T = 256;
    const int NB = (N + 255) / 256;       // 391 scan blocks

    // --- build CSR + dinv ---
    hipMemsetAsync(counts, 0, (size_t)N * sizeof(int), stream);
    hist_kernel<<<(E + T - 1) / T, T, 0, stream>>>(dst, counts, E);
    dinv_kernel<<<NB, T, 0, stream>>>(counts, dinv, N);
    scan1_kernel<<<NB, T, 0, stream>>>(counts, rowptr, bsums, N);
    scan2_kernel<<<1, 512, 0, stream>>>(bsums, NB);
    scan3_kernel<<<NB, T, 0, stream>>>(rowptr, bsums, N);
    scatter_kernel<<<(E + T - 1) / T, T, 0, stream>>>(src, dst, dinv, rowptr, edges, E);
    // rowptr now holds row-end offsets.

    // --- layer 1: x @ W1 -> A; aggregate+relu -> B ---
    gemm_kernel<64, 64><<<(N + 3) / 4, T, 0, stream>>>(x, W1, A, N);
    agg_kernel<64, true><<<(N * 64 + T - 1) / T, T, 0, stream>>>(edges, rowptr, dinv, A, b1, B, N);

    // --- layer 2: B @ W2 -> A[N,32]; aggregate+relu -> B ---
    gemm_kernel<64, 32><<<(N + 7) / 8, T, 0, stream>>>(B, W2, A, N);
    agg_kernel<32, true><<<(N * 32 + T - 1) / T, T, 0, stream>>>(edges, rowptr, dinv, A, b2, B, N);

    // --- layer 3: B @ W3 -> A[N,2]; aggregate -> d_out ---
    gemm_kernel<32, 2><<<(N + 127) / 128, T, 0, stream>>>(B, W3, A, N);
    agg_kernel<2, false><<<(N * 2 + T - 1) / T, T, 0, stream>>>(edges, rowptr, dinv, A, b3, out, N);
}

// Round 3
// 474.833 us; speedup vs baseline: 1.9041x; 1.2616x over previous
//
#include <hip/hip_runtime.h>

#define N_NODES 100000
#define N_EDGES 1600000

// ---------------------------------------------------------------------------
// int in-degree histogram (counts pre-zeroed)
__global__ void hist_kernel(const int* __restrict__ dst, int* __restrict__ counts, int E) {
    int e = blockIdx.x * blockDim.x + threadIdx.x;
    if (e < E) atomicAdd(&counts[dst[e]], 1);
}

// dinv[i] = rsqrt(indeg + 1)   (+1 = self loop)
__global__ void dinv_kernel(const int* __restrict__ counts, float* __restrict__ dinv, int n) {
    int i = blockIdx.x * blockDim.x + threadIdx.x;
    if (i < n) dinv[i] = rsqrtf((float)counts[i] + 1.0f);
}

// --- 3-kernel exclusive scan of counts[n] -> rowptr[n] ----------------------
__global__ void scan1_kernel(const int* __restrict__ counts, int* __restrict__ rowptr,
                             int* __restrict__ bsums, int n) {
    __shared__ int s[256];
    int i = blockIdx.x * 256 + threadIdx.x;
    int v = (i < n) ? counts[i] : 0;
    s[threadIdx.x] = v;
    __syncthreads();
    for (int off = 1; off < 256; off <<= 1) {
        int t = (threadIdx.x >= off) ? s[threadIdx.x - off] : 0;
        __syncthreads();
        s[threadIdx.x] += t;
        __syncthreads();
    }
    if (i < n) rowptr[i] = s[threadIdx.x] - v;           // exclusive
    if (threadIdx.x == 255) bsums[blockIdx.x] = s[255];  // block total
}

__global__ void scan2_kernel(int* __restrict__ bsums, int nb) {
    __shared__ int s[512];
    int t = threadIdx.x;
    int v = (t < nb) ? bsums[t] : 0;
    s[t] = v;
    __syncthreads();
    for (int off = 1; off < 512; off <<= 1) {
        int u = (t >= off) ? s[t - off] : 0;
        __syncthreads();
        s[t] += u;
        __syncthreads();
    }
    if (t < nb) bsums[t] = s[t] - v;                     // exclusive
}

__global__ void scan3_kernel(int* __restrict__ rowptr, const int* __restrict__ bsums, int n) {
    int i = blockIdx.x * 256 + threadIdx.x;
    if (i < n) rowptr[i] += bsums[blockIdx.x];
}

// --- scatter edges into CSR order; rowptr is consumed as cursors ------------
// After this kernel rowptr[d] == original rowptr[d+1]  (i.e. row END of d).
__global__ void scatter_kernel(const int* __restrict__ src, const int* __restrict__ dst,
                               const float* __restrict__ dinv, int* __restrict__ rowptr,
                               int2* __restrict__ edges, int E) {
    int e = blockIdx.x * blockDim.x + threadIdx.x;
    if (e >= E) return;
    int s = src[e];
    int d = dst[e];
    float w = dinv[s] * dinv[d];
    int pos = atomicAdd(&rowptr[d], 1);
    edges[pos] = make_int2(s, __float_as_int(w));
}

// ---------------------------------------------------------------------------
// out[n, FOUT] = in[n, FIN] @ W[FIN, FOUT]
template <int FIN, int FOUT>
__global__ void gemm_kernel(const float* __restrict__ in, const float* __restrict__ W,
                            float* __restrict__ out, int n) {
    __shared__ float sW[FIN * FOUT];
    for (int i = threadIdx.x; i < FIN * FOUT; i += blockDim.x) sW[i] = W[i];
    __syncthreads();
    constexpr int ROWS = 256 / FOUT;
    int r = blockIdx.x * ROWS + threadIdx.x / FOUT;
    int c = threadIdx.x % FOUT;
    if (r >= n) return;
    float acc = 0.f;
#pragma unroll
    for (int k = 0; k < FIN; k++) acc += in[r * FIN + k] * sW[k * FOUT + c];
    out[r * FOUT + c] = acc;
}

// ---------------------------------------------------------------------------
// Gather-side aggregation, zero atomics, finalize fused, 4x unrolled for MLP
// (4 independent gather chains per wave instead of 1).
template <int F, bool RELU>
__global__ void agg_kernel(const int2* __restrict__ edges, const int* __restrict__ rowend,
                           const float* __restrict__ dinv, const float* __restrict__ h,
                           const float* __restrict__ b, float* __restrict__ out, int n) {
    int g = (blockIdx.x * blockDim.x + threadIdx.x) / F;   // node
    int lane = threadIdx.x % F;                            // feature
    if (g >= n) return;
    int end = rowend[g];
    int j = (g == 0) ? 0 : rowend[g - 1];
    float di = dinv[g];
    float hs = h[g * F + lane];

    float acc0 = 0.f, acc1 = 0.f, acc2 = 0.f, acc3 = 0.f;
    for (; j + 4 <= end; j += 4) {
        int2 e0 = edges[j];
        int2 e1 = edges[j + 1];
        int2 e2 = edges[j + 2];
        int2 e3 = edges[j + 3];
        float h0 = h[e0.x * F + lane];
        float h1 = h[e1.x * F + lane];
        float h2 = h[e2.x * F + lane];
        float h3 = h[e3.x * F + lane];
        acc0 += __int_as_float(e0.y) * h0;
        acc1 += __int_as_float(e1.y) * h1;
        acc2 += __int_as_float(e2.y) * h2;
        acc3 += __int_as_float(e3.y) * h3;
    }
    for (; j < end; j++) {
        int2 e = edges[j];
        acc0 += __int_as_float(e.y) * h[e.x * F + lane];
    }
    float acc = (acc0 + acc1) + (acc2 + acc3);
    float v = acc + di * di * hs + b[lane];
    out[g * F + lane] = RELU ? fmaxf(v, 0.f) : v;
}

// ---------------------------------------------------------------------------
extern "C" void kernel_launch(void* const* d_in, const int* in_sizes, int n_in,
                              void* d_out, int out_size, void* d_ws, size_t ws_size,
                              hipStream_t stream) {
    const float* x  = (const float*)d_in[0];           // [N, 64]
    const int* ei   = (const int*)d_in[1];             // [2, E]
    const float* W1 = (const float*)d_in[2];
    const float* b1 = (const float*)d_in[3];
    const float* W2 = (const float*)d_in[4];
    const float* b2 = (const float*)d_in[5];
    const float* W3 = (const float*)d_in[6];
    const float* b3 = (const float*)d_in[7];
    float* out = (float*)d_out;                        // [N, 2]

    const int N = N_NODES;
    const int E = N_EDGES;
    const int* src = ei;
    const int* dst = ei + E;

    // workspace layout (16B-aligned carve)
    char* p = (char*)d_ws;
    int*   counts = (int*)p;              p += ((size_t)N * 4 + 15) / 16 * 16;
    int*   rowptr = (int*)p;              p += ((size_t)N * 4 + 15) / 16 * 16;
    int*   bsums  = (int*)p;              p += 512 * 4;
    float* dinv   = (float*)p;            p += ((size_t)N * 4 + 15) / 16 * 16;
    int2*  edges  = (int2*)p;             p += (size_t)E * 8;
    float* A      = (float*)p;            p += (size_t)N * 64 * 4;
    float* B      = (float*)p;

    const int T = 256;
    const int NB = (N + 255) / 256;       // 391 scan blocks

    // --- build CSR + dinv ---
    hipMemsetAsync(counts, 0, (size_t)N * sizeof(int), stream);
    hist_kernel<<<(E + T - 1) / T, T, 0, stream>>>(dst, counts, E);
    dinv_kernel<<<NB, T, 0, stream>>>(counts, dinv, N);
    scan1_kernel<<<NB, T, 0, stream>>>(counts, rowptr, bsums, N);
    scan2_kernel<<<1, 512, 0, stream>>>(bsums, NB);
    scan3_kernel<<<NB, T, 0, stream>>>(rowptr, bsums, N);
    scatter_kernel<<<(E + T - 1) / T, T, 0, stream>>>(src, dst, dinv, rowptr, edges, E);
    // rowptr now holds row-end offsets.

    // --- layer 1: x @ W1 -> A; aggregate+relu -> B ---
    gemm_kernel<64, 64><<<(N + 3) / 4, T, 0, stream>>>(x, W1, A, N);
    agg_kernel<64, true><<<(N * 64 + T - 1) / T, T, 0, stream>>>(edges, rowptr, dinv, A, b1, B, N);

    // --- layer 2: B @ W2 -> A[N,32]; aggregate+relu -> B ---
    gemm_kernel<64, 32><<<(N + 7) / 8, T, 0, stream>>>(B, W2, A, N);
    agg_kernel<32, true><<<(N * 32 + T - 1) / T, T, 0, stream>>>(edges, rowptr, dinv, A, b2, B, N);

    // --- layer 3: B @ W3 -> A[N,2]; aggregate -> d_out ---
    gemm_kernel<32, 2><<<(N + 127) / 128, T, 0, stream>>>(B, W3, A, N);
    agg_kernel<2, false><<<(N * 2 + T - 1) / T, T, 0, stream>>>(edges, rowptr, dinv, A, b3, out, N);
}